// Round 5
// baseline (152.248 us; speedup 1.0000x reference)
//
#include <hip/hip_runtime.h>

#define B 2
#define W 4096
#define R 8
#define D 32
#define L 64
#define C (W / L)     // 64 chunks
#define NBLK (B * C)  // 128 blocks <= 256 CUs: all co-resident, manual barrier safe

// gamma^e for e in [0,63] via repeated squaring: 6 mul+sel, no libm.
__device__ __forceinline__ float gpow6(float g, int e) {
    float p = 1.f;
    float b = g;
#pragma unroll
    for (int bit = 0; bit < 6; ++bit) {
        p = (e & (1 << bit)) ? p * b : p;
        b *= b;
    }
    return p;
}

// ---------------------------------------------------------------------------
// Single fused kernel, plain launch (no cooperative API), 128 x 512.
// Phase A: stage q,k,h once (decay folded at load: qg=q*g^i, kg=k*g^-j),
//          compute S_loc (even/odd-j split), publish via agent-scope atomics.
// Barrier: device-scope counter (ws+128KB, memset to 0 each launch).
// Phase B: waves 0-3 scan P_c (63 loads all in flight, predicated Horner)
//          overlapped with waves 4-7 building A^T; then triangular output.
// Cross-XCD correctness: all ws traffic uses __hip_atomic_* at AGENT scope
// (per-XCD L2s are not coherent; atomics hit the device coherence point).
// ---------------------------------------------------------------------------
__global__ __launch_bounds__(512) void k_fused(const float* __restrict__ qin,
                                               const float* __restrict__ kin,
                                               const float* __restrict__ hin,
                                               const float* __restrict__ gamma_vec,
                                               float* __restrict__ ws_state,
                                               unsigned int* __restrict__ counter,
                                               float* __restrict__ out) {
    __shared__ float sqg[R][L];                         // 2 KB, stride-1 in i
    __shared__ float skg[R][L];                         // 2 KB
    __shared__ float sk[L][R];                          // 2 KB (raw k for S_loc)
    __shared__ float sh[L][D];                          // 8 KB
    __shared__ __align__(16) float sAT[L][L + 4];       // A^T [j][i], pad 68 (17 KB)
    __shared__ float s0[R][D];                          // gamma_r * P_c[r,d]
    __shared__ float part[2][R][D];                     // 2 KB
    const int blk = blockIdx.x;
    const int b = blk / C, c = blk % C;
    const int t = threadIdx.x;
    const size_t row0 = (size_t)b * W + (size_t)c * L;

    // ---- Phase A staging. q,k chunks are 512 floats = 128 float4 EACH. ----
    ((float4*)sh)[t] = ((const float4*)(hin + row0 * D))[t];    // 512 x float4
    if (t < 128) {                       // q -> qg = q * gamma^i
        const int i = t >> 1, r0 = (t & 1) * 4;
        const float4 v = ((const float4*)(qin + row0 * R))[t];
        sqg[r0 + 0][i] = v.x * gpow6(gamma_vec[r0 + 0], i);
        sqg[r0 + 1][i] = v.y * gpow6(gamma_vec[r0 + 1], i);
        sqg[r0 + 2][i] = v.z * gpow6(gamma_vec[r0 + 2], i);
        sqg[r0 + 3][i] = v.w * gpow6(gamma_vec[r0 + 3], i);
    } else if (t < 256) {                // k -> raw sk + kg = k * gamma^-j
        const int u = t - 128;
        const int i = u >> 1, r0 = (u & 1) * 4;
        const float4 v = ((const float4*)(kin + row0 * R))[u];
        sk[i][r0 + 0] = v.x; sk[i][r0 + 1] = v.y;
        sk[i][r0 + 2] = v.z; sk[i][r0 + 3] = v.w;
        skg[r0 + 0][i] = v.x * gpow6(1.f / gamma_vec[r0 + 0], i);
        skg[r0 + 1][i] = v.y * gpow6(1.f / gamma_vec[r0 + 1], i);
        skg[r0 + 2][i] = v.z * gpow6(1.f / gamma_vec[r0 + 2], i);
        skg[r0 + 3][i] = v.w * gpow6(1.f / gamma_vec[r0 + 3], i);
    }
    __syncthreads();

    // ---- Phase A: local state, even/odd-j split (32-deep chain, g^2 step) ----
    {
        const int half = t >> 8;         // 0: even j, 1: odd j
        const int rd = t & 255;
        const int r = rd >> 5, d = rd & 31;
        const float g = gamma_vec[r];
        const float g2 = g * g;
        float S = 0.f;
#pragma unroll
        for (int m = 0; m < 32; ++m) {
            const int j = 2 * m + half;
            S = S * g2 + sk[j][r] * sh[j][d];
        }
        part[half][r][d] = S;
        __syncthreads();
        if (t < 256) {  // g^(63-j): odd j -> part[1]; even j -> g * part[0]
            const float val = part[1][r][d] + g * part[0][r][d];
            __hip_atomic_store(&ws_state[(size_t)blk * 256 + rd], val,
                               __ATOMIC_RELAXED, __HIP_MEMORY_SCOPE_AGENT);
        }
    }
    __threadfence();                     // drain this thread's stores to coherent point
    __syncthreads();

    // ---- manual grid barrier: device-scope counter, zeroed per launch ----
    if (t == 0) {
        atomicAdd(counter, 1u);          // device-scope by default on CDNA
        while (__hip_atomic_load(counter, __ATOMIC_ACQUIRE,
                                 __HIP_MEMORY_SCOPE_AGENT) < NBLK) {}
    }
    __syncthreads();

    // ---- Phase B: scan (waves 0-3) in parallel with A-build (waves 4-7) ----
    if (t < 256) {
        // P = sum_{cc<c} (g^64)^(c-1-cc) * S_loc[cc]; all 63 loads in flight.
        const int r = t >> 5;
        const float g = gamma_vec[r];
        float gL = g;
#pragma unroll
        for (int s = 0; s < 6; ++s) gL *= gL;           // gamma^64
        float* wsp = ws_state + (size_t)b * C * 256 + t;
        float v[C - 1];
#pragma unroll
        for (int cc = 0; cc < C - 1; ++cc)              // every chunk wrote S_loc:
            v[cc] = __hip_atomic_load(wsp + (size_t)cc * 256,   // all values real
                                      __ATOMIC_RELAXED, __HIP_MEMORY_SCOPE_AGENT);
        float P = 0.f;
#pragma unroll
        for (int cc = 0; cc < C - 1; ++cc)              // predicated Horner
            P = (cc < c) ? P * gL + v[cc] : P;
        s0[r][t & 31] = g * P;           // fold gamma^1: out uses qg * (g*P)
    } else {
        // A-build: 256 threads, 16 entries each. i per-lane (stride-1 reads),
        // j wave-uniform (broadcast kg reads).
        const int u = t - 256;
        const int i = u & 63;
        const int w2 = u >> 6;           // 0..3, wave-uniform
        float qreg[R];
#pragma unroll
        for (int r = 0; r < R; ++r) qreg[r] = sqg[r][i];
#pragma unroll
        for (int p = 0; p < 16; ++p) {
            const int j = w2 + 4 * p;
            float a = 0.f;
#pragma unroll
            for (int r = 0; r < R; ++r) a += qreg[r] * skg[r][j];
            sAT[j][i] = (j <= i) ? a : 0.f;
        }
    }
    __syncthreads();

    // ---- outputs: thread -> (ig, d), i = ig*4 + s ----
    const int d = t & 31;
    const int ig = t >> 5;               // 0..15
    float pr[R];
#pragma unroll
    for (int r = 0; r < R; ++r) pr[r] = s0[r][d];
    float acc[4];
#pragma unroll
    for (int s = 0; s < 4; ++s) {
        const int i2 = ig * 4 + s;
        float a = 0.f;
#pragma unroll
        for (int r = 0; r < R; ++r) a += sqg[r][i2] * pr[r];   // broadcast reads
        acc[s] = a;
    }
    const int jmax = ig * 4 + 3;         // triangular: A^T[j][i]=0 above diag
    for (int j = 0; j <= jmax; ++j) {
        const float hv = sh[j][d];                          // conflict-free b32
        const float4 av = *(const float4*)&sAT[j][ig * 4];  // b128 broadcast
        acc[0] += av.x * hv; acc[1] += av.y * hv;
        acc[2] += av.z * hv; acc[3] += av.w * hv;
    }
#pragma unroll
    for (int s = 0; s < 4; ++s)
        out[(row0 + (size_t)(ig * 4 + s)) * D + d] = acc[s];
}

extern "C" void kernel_launch(void* const* d_in, const int* in_sizes, int n_in,
                              void* d_out, int out_size, void* d_ws, size_t ws_size,
                              hipStream_t stream) {
    const float* q  = (const float*)d_in[0];   // [B,W,R]
    const float* k  = (const float*)d_in[1];   // [B,W,R]
    const float* h  = (const float*)d_in[2];   // [B,W,D]
    const float* gv = (const float*)d_in[3];   // [R]
    // d_in[4] (causal_mask) and d_in[5] (decay_diff) are implied analytically.
    float* out = (float*)d_out;                // [B,W,D] fp32
    float* ws  = (float*)d_ws;                 // [0,128KB): S_loc; +128KB: counter

    unsigned int* counter = (unsigned int*)((char*)d_ws + 128 * 1024);
    hipMemsetAsync(counter, 0, sizeof(unsigned int), stream);  // ws re-poisoned
                                                               // each iter: must re-zero
    k_fused<<<NBLK, 512, 0, stream>>>(q, k, h, gv, ws, counter, out);
}

// Round 6
// 133.768 us; speedup vs baseline: 1.1382x; 1.1382x over previous
//
#include <hip/hip_runtime.h>

#define B 2
#define W 4096
#define R 8
#define D 32
#define L 64
#define C (W / L)   // 64 chunks

// gamma^e for e in [0,63] via repeated squaring: 6 mul+sel, no libm.
__device__ __forceinline__ float gpow6(float g, int e) {
    float p = 1.f;
    float b = g;
#pragma unroll
    for (int bit = 0; bit < 6; ++bit) {
        p = (e & (1 << bit)) ? p * b : p;
        b *= b;
    }
    return p;
}

// ---------------------------------------------------------------------------
// Kernel 1: per-chunk local decayed state (identical to the proven r3 version)
//   S_loc[b,c,r,d] = sum_{j=0..L-1} gamma_r^(L-1-j) * k[b,cL+j,r] * h[b,cL+j,d]
// ---------------------------------------------------------------------------
__global__ __launch_bounds__(512) void k_local(const float* __restrict__ kin,
                                               const float* __restrict__ hin,
                                               const float* __restrict__ gamma_vec,
                                               float* __restrict__ ws_state) {
    __shared__ float sk[L][R];        // 2 KB
    __shared__ float sh[L][D];        // 8 KB
    __shared__ float part[2][R][D];   // 2 KB
    const int blk = blockIdx.x;
    const int b = blk / C, c = blk % C;
    const int t = threadIdx.x;
    const float* kp = kin + ((size_t)b * W + (size_t)c * L) * R;   // [L][R]
    const float* hp = hin + ((size_t)b * W + (size_t)c * L) * D;   // [L][D]
    ((float*)sk)[t] = kp[t];                       // 512 floats
    ((float4*)sh)[t] = ((const float4*)hp)[t];     // 2048 floats
    __syncthreads();
    const int half = t >> 8;          // 0: even j, 1: odd j
    const int rd = t & 255;
    const int r = rd >> 5, d = rd & 31;
    const float g = gamma_vec[r];
    const float g2 = g * g;
    float S = 0.f;
#pragma unroll
    for (int m = 0; m < 32; ++m) {
        const int j = 2 * m + half;
        S = S * g2 + sk[j][r] * sh[j][d];
    }
    part[half][r][d] = S;
    __syncthreads();
    if (t < 256) {
        // g^(63-j): odd j -> (g^2)^((63-j)/2) = part[1]; even j -> g*(g^2)^((62-j)/2)
        ws_state[(size_t)(b * C + c) * R * D + rd] = part[1][r][d] + g * part[0][r][d];
    }
}

// ---------------------------------------------------------------------------
// Kernel 2: fused scan + output, latency-optimal schedule:
//   pre-barrier : waves 0-3 issue ALL 63 scan loads (one latency exposure);
//                 waves 4-7 stage h + q(fold g^i) + k(fold g^-j)
//   barrier     : single drain -- everyone waits one memory round-trip
//   post-barrier: waves 0-3 predicated Horner -> s0   (pure VALU, ~250cy)
//              || waves 4-7 build A^T[j][i]           (LDS+VALU, ~600cy)
//   barrier; all 512: out = qg.(g*P) + A.h (triangular, b128 reads)
// ---------------------------------------------------------------------------
__global__ __launch_bounds__(512) void k_out(const float* __restrict__ qin,
                                             const float* __restrict__ kin,
                                             const float* __restrict__ hin,
                                             const float* __restrict__ gamma_vec,
                                             const float* __restrict__ ws_state,
                                             float* __restrict__ out) {
    __shared__ float sqg[R][L];                         // 2 KB, stride-1 in i
    __shared__ float skg[R][L];                         // 2 KB
    __shared__ float sh[L][D];                          // 8 KB
    __shared__ __align__(16) float sAT[L][L + 4];       // A^T [j][i], pad 68 (17 KB)
    __shared__ float s0[R][D];                          // gamma_r * P_c[r,d]
    const int blk = blockIdx.x;
    const int b = blk / C, c = blk % C;
    const int t = threadIdx.x;
    const size_t row0 = (size_t)b * W + (size_t)c * L;

    float v[C - 1];                      // scan burst (waves 0-3 only), static idx
    if (t < 256) {
        // ---- issue all 63 chunk-state loads; every chunk wrote real data ----
        const float* wsp = ws_state + (size_t)b * C * 256 + t;
#pragma unroll
        for (int cc = 0; cc < C - 1; ++cc)
            v[cc] = wsp[(size_t)cc * 256];              // 1 KB/row, coalesced
    } else {
        // ---- staging half (waves 4-7); q,k chunks = 128 float4 each ----
        const int u = t - 256;
        const float* hp = hin + row0 * D;
        ((float4*)sh)[u]       = ((const float4*)hp)[u];        // 512 float4 total
        ((float4*)sh)[u + 256] = ((const float4*)hp)[u + 256];
        const int i = (u & 127) >> 1;    // each float4 covers (i, r0..r0+3)
        const int r0 = (u & 1) * 4;
        if (u < 128) {                   // waves 4-5: q -> qg = q * gamma^i
            const float4 q4 = ((const float4*)(qin + row0 * R))[u];
            sqg[r0 + 0][i] = q4.x * gpow6(gamma_vec[r0 + 0], i);
            sqg[r0 + 1][i] = q4.y * gpow6(gamma_vec[r0 + 1], i);
            sqg[r0 + 2][i] = q4.z * gpow6(gamma_vec[r0 + 2], i);
            sqg[r0 + 3][i] = q4.w * gpow6(gamma_vec[r0 + 3], i);
        } else {                         // waves 6-7: k -> kg = k * gamma^-j
            const float4 k4 = ((const float4*)(kin + row0 * R))[u - 128];
            skg[r0 + 0][i] = k4.x * gpow6(1.f / gamma_vec[r0 + 0], i);
            skg[r0 + 1][i] = k4.y * gpow6(1.f / gamma_vec[r0 + 1], i);
            skg[r0 + 2][i] = k4.z * gpow6(1.f / gamma_vec[r0 + 2], i);
            skg[r0 + 3][i] = k4.w * gpow6(1.f / gamma_vec[r0 + 3], i);
        }
    }
    __syncthreads();                     // one drain: scan burst + staging together

    if (t < 256) {
        // ---- predicated Horner: P = sum_{cc<c} (g^64)^(c-1-cc) * S_loc[cc] ----
        const int r = t >> 5;
        const float g = gamma_vec[r];
        float gL = g;
#pragma unroll
        for (int s = 0; s < 6; ++s) gL *= gL;           // gamma^64
        float P = 0.f;
#pragma unroll
        for (int cc = 0; cc < C - 1; ++cc)
            P = (cc < c) ? P * gL + v[cc] : P;
        s0[r][t & 31] = g * P;           // fold gamma^1: out uses qg * (g*P)
    } else {
        // ---- A-build: 256 threads, 16 entries each. i per-lane (stride-1),
        //      j wave-uniform (broadcast kg reads). ----
        const int u = t - 256;
        const int i = u & 63;
        const int w2 = u >> 6;           // 0..3, wave-uniform
        float qreg[R];
#pragma unroll
        for (int r = 0; r < R; ++r) qreg[r] = sqg[r][i];
#pragma unroll
        for (int p = 0; p < 16; ++p) {
            const int j = w2 + 4 * p;
            float a = 0.f;
#pragma unroll
            for (int r = 0; r < R; ++r) a += qreg[r] * skg[r][j];
            sAT[j][i] = (j <= i) ? a : 0.f;
        }
    }
    __syncthreads();

    // ---- outputs: thread -> (ig, d), i = ig*4 + s ----
    const int d = t & 31;
    const int ig = t >> 5;               // 0..15
    float pr[R];
#pragma unroll
    for (int r = 0; r < R; ++r) pr[r] = s0[r][d];
    float acc[4];
#pragma unroll
    for (int s = 0; s < 4; ++s) {
        const int i2 = ig * 4 + s;
        float a = 0.f;
#pragma unroll
        for (int r = 0; r < R; ++r) a += sqg[r][i2] * pr[r];   // broadcast reads
        acc[s] = a;
    }
    const int jmax = ig * 4 + 3;         // triangular: A^T[j][i]=0 above diag
    for (int j = 0; j <= jmax; ++j) {
        const float hv = sh[j][d];                          // conflict-free b32
        const float4 av = *(const float4*)&sAT[j][ig * 4];  // b128 broadcast
        acc[0] += av.x * hv; acc[1] += av.y * hv;
        acc[2] += av.z * hv; acc[3] += av.w * hv;
    }
#pragma unroll
    for (int s = 0; s < 4; ++s)
        out[(row0 + (size_t)(ig * 4 + s)) * D + d] = acc[s];
}

extern "C" void kernel_launch(void* const* d_in, const int* in_sizes, int n_in,
                              void* d_out, int out_size, void* d_ws, size_t ws_size,
                              hipStream_t stream) {
    const float* q  = (const float*)d_in[0];   // [B,W,R]
    const float* k  = (const float*)d_in[1];   // [B,W,R]
    const float* h  = (const float*)d_in[2];   // [B,W,D]
    const float* gv = (const float*)d_in[3];   // [R]
    // d_in[4] (causal_mask) and d_in[5] (decay_diff) are implied analytically.
    float* out = (float*)d_out;                // [B,W,D] fp32
    float* ws  = (float*)d_ws;                 // B*C*R*D*4 = 128 KB used

    k_local<<<B * C, 512, 0, stream>>>(k, h, gv, ws);
    k_out  <<<B * C, 512, 0, stream>>>(q, k, h, gv, ws, out);
}

// Round 7
// 133.340 us; speedup vs baseline: 1.1418x; 1.0032x over previous
//
#include <hip/hip_runtime.h>

#define B 2
#define W 4096
#define R 8
#define D 32
#define L 64
#define C (W / L)     // 64 chunks
#define HL 32         // half-chunk length
#define NH (W / HL)   // 128 half-chunks per batch

// gamma^e for e in [0,63] via repeated squaring: 6 mul+sel, no libm.
__device__ __forceinline__ float gpow6(float g, int e) {
    float p = 1.f;
    float b = g;
#pragma unroll
    for (int bit = 0; bit < 6; ++bit) {
        p = (e & (1 << bit)) ? p * b : p;
        b *= b;
    }
    return p;
}

// ---------------------------------------------------------------------------
// Kernel 1: per-HALF-chunk local decayed state. 256 blocks = 1 per CU.
//   H[b,m,r,d] = sum_{jj=0..31} gamma_r^(31-jj) * k[b,m*32+jj,r] * h[b,m*32+jj,d]
// Even/odd-jj split: 16-deep serial chain with g^2 step.
// ---------------------------------------------------------------------------
__global__ __launch_bounds__(512) void k_local(const float* __restrict__ kin,
                                               const float* __restrict__ hin,
                                               const float* __restrict__ gamma_vec,
                                               float* __restrict__ ws_state) {
    __shared__ float sk[HL][R];       // 1 KB
    __shared__ float sh[HL][D];       // 4 KB
    __shared__ float part[2][R][D];   // 2 KB
    const int blk = blockIdx.x;
    const int b = blk >> 7, m = blk & 127;
    const int t = threadIdx.x;
    const size_t base = (size_t)b * W + (size_t)m * HL;
    if (t < 256) {                    // h: 1024 floats = 256 float4
        ((float4*)sh)[t] = ((const float4*)(hin + base * D))[t];
    } else if (t < 320) {             // k: 256 floats = 64 float4
        const int u = t - 256;
        const int row = u >> 1, c0 = (u & 1) * 4;
        const float4 v = ((const float4*)(kin + base * R))[u];
        sk[row][c0 + 0] = v.x; sk[row][c0 + 1] = v.y;
        sk[row][c0 + 2] = v.z; sk[row][c0 + 3] = v.w;
    }
    __syncthreads();
    const int half = t >> 8;          // 0: even jj, 1: odd jj
    const int rd = t & 255;
    const int r = rd >> 5, d = rd & 31;
    const float g = gamma_vec[r];
    const float g2 = g * g;
    float S = 0.f;
#pragma unroll
    for (int u = 0; u < 16; ++u) {    // 16-deep chain, g^2 step
        const int jj = 2 * u + half;
        S = S * g2 + sk[jj][r] * sh[jj][d];
    }
    part[half][r][d] = S;
    __syncthreads();
    if (t < 256) {
        // gamma^(31-jj): odd jj -> part[1]; even jj -> g * part[0]
        ws_state[(size_t)blk * 256 + rd] = part[1][r][d] + g * part[0][r][d];
    }
}

// ---------------------------------------------------------------------------
// Kernel 2: fused scan + output (round-6 schedule, half-chunk scan):
//   pre-barrier : waves 0-3 issue ALL 126 half-chunk loads (one latency
//                 exposure); waves 4-7 stage h + q(fold g^i) + k(fold g^-j)
//   barrier     : single drain
//   post-barrier: waves 0-3: P = sum_{m<2c} (g^32)^(2c-1-m) H_m  (Horner)
//              || waves 4-7: build A^T[j][i] = sum_r qg[r][i]kg[r][j]
//   barrier; all 512: out = qg.(g*P) + A.h (triangular, b128 reads)
// ---------------------------------------------------------------------------
__global__ __launch_bounds__(512) void k_out(const float* __restrict__ qin,
                                             const float* __restrict__ kin,
                                             const float* __restrict__ hin,
                                             const float* __restrict__ gamma_vec,
                                             const float* __restrict__ ws_state,
                                             float* __restrict__ out) {
    __shared__ float sqg[R][L];                         // 2 KB, stride-1 in i
    __shared__ float skg[R][L];                         // 2 KB
    __shared__ float sh[L][D];                          // 8 KB
    __shared__ __align__(16) float sAT[L][L + 4];       // A^T [j][i], pad 68 (17 KB)
    __shared__ float s0[R][D];                          // gamma_r * P_c[r,d]
    const int blk = blockIdx.x;
    const int b = blk / C, c = blk % C;
    const int t = threadIdx.x;
    const size_t row0 = (size_t)b * W + (size_t)c * L;

    float v[NH - 2];                     // 126 half-chunk states, static idx
    if (t < 256) {
        // ---- issue all 126 loads; every half-chunk wrote real data ----
        const float* wsp = ws_state + (size_t)b * NH * 256 + t;
#pragma unroll
        for (int m = 0; m < NH - 2; ++m)
            v[m] = wsp[(size_t)m * 256];                // 1 KB/row, coalesced
    } else {
        // ---- staging half (waves 4-7); q,k chunks = 128 float4 each ----
        const int u = t - 256;
        const float* hp = hin + row0 * D;
        ((float4*)sh)[u]       = ((const float4*)hp)[u];        // 512 float4 total
        ((float4*)sh)[u + 256] = ((const float4*)hp)[u + 256];
        const int i = (u & 127) >> 1;    // each float4 covers (i, r0..r0+3)
        const int r0 = (u & 1) * 4;
        if (u < 128) {                   // waves 4-5: q -> qg = q * gamma^i
            const float4 q4 = ((const float4*)(qin + row0 * R))[u];
            sqg[r0 + 0][i] = q4.x * gpow6(gamma_vec[r0 + 0], i);
            sqg[r0 + 1][i] = q4.y * gpow6(gamma_vec[r0 + 1], i);
            sqg[r0 + 2][i] = q4.z * gpow6(gamma_vec[r0 + 2], i);
            sqg[r0 + 3][i] = q4.w * gpow6(gamma_vec[r0 + 3], i);
        } else {                         // waves 6-7: k -> kg = k * gamma^-j
            const float4 k4 = ((const float4*)(kin + row0 * R))[u - 128];
            skg[r0 + 0][i] = k4.x * gpow6(1.f / gamma_vec[r0 + 0], i);
            skg[r0 + 1][i] = k4.y * gpow6(1.f / gamma_vec[r0 + 1], i);
            skg[r0 + 2][i] = k4.z * gpow6(1.f / gamma_vec[r0 + 2], i);
            skg[r0 + 3][i] = k4.w * gpow6(1.f / gamma_vec[r0 + 3], i);
        }
    }
    __syncthreads();                     // one drain: scan burst + staging together

    if (t < 256) {
        // ---- predicated Horner over half-chunks, step gamma^32 ----
        const int r = t >> 5;
        const float g = gamma_vec[r];
        float g32 = g;
#pragma unroll
        for (int s = 0; s < 5; ++s) g32 *= g32;         // gamma^32
        const int mlim = 2 * c;          // half-chunks strictly before chunk c
        float P = 0.f;
#pragma unroll
        for (int m = 0; m < NH - 2; ++m)
            P = (m < mlim) ? P * g32 + v[m] : P;
        s0[r][t & 31] = g * P;           // fold gamma^1: out uses qg * (g*P)
    } else {
        // ---- A-build: 256 threads, 16 entries each. i per-lane (stride-1),
        //      j wave-uniform (broadcast kg reads). ----
        const int u = t - 256;
        const int i = u & 63;
        const int w2 = u >> 6;           // 0..3, wave-uniform
        float qreg[R];
#pragma unroll
        for (int r = 0; r < R; ++r) qreg[r] = sqg[r][i];
#pragma unroll
        for (int p = 0; p < 16; ++p) {
            const int j = w2 + 4 * p;
            float a = 0.f;
#pragma unroll
            for (int r = 0; r < R; ++r) a += qreg[r] * skg[r][j];
            sAT[j][i] = (j <= i) ? a : 0.f;
        }
    }
    __syncthreads();

    // ---- outputs: thread -> (ig, d), i = ig*4 + s ----
    const int d = t & 31;
    const int ig = t >> 5;               // 0..15
    float pr[R];
#pragma unroll
    for (int r = 0; r < R; ++r) pr[r] = s0[r][d];
    float acc[4];
#pragma unroll
    for (int s = 0; s < 4; ++s) {
        const int i2 = ig * 4 + s;
        float a = 0.f;
#pragma unroll
        for (int r = 0; r < R; ++r) a += sqg[r][i2] * pr[r];   // broadcast reads
        acc[s] = a;
    }
    const int jmax = ig * 4 + 3;         // triangular: A^T[j][i]=0 above diag
    for (int j = 0; j <= jmax; ++j) {
        const float hv = sh[j][d];                          // conflict-free b32
        const float4 av = *(const float4*)&sAT[j][ig * 4];  // b128 broadcast
        acc[0] += av.x * hv; acc[1] += av.y * hv;
        acc[2] += av.z * hv; acc[3] += av.w * hv;
    }
#pragma unroll
    for (int s = 0; s < 4; ++s)
        out[(row0 + (size_t)(ig * 4 + s)) * D + d] = acc[s];
}

extern "C" void kernel_launch(void* const* d_in, const int* in_sizes, int n_in,
                              void* d_out, int out_size, void* d_ws, size_t ws_size,
                              hipStream_t stream) {
    const float* q  = (const float*)d_in[0];   // [B,W,R]
    const float* k  = (const float*)d_in[1];   // [B,W,R]
    const float* h  = (const float*)d_in[2];   // [B,W,D]
    const float* gv = (const float*)d_in[3];   // [R]
    // d_in[4] (causal_mask) and d_in[5] (decay_diff) are implied analytically.
    float* out = (float*)d_out;                // [B,W,D] fp32
    float* ws  = (float*)d_ws;                 // B*NH*R*D*4 = 256 KB used

    k_local<<<B * NH, 512, 0, stream>>>(k, h, gv, ws);   // 256 blocks = 1/CU
    k_out  <<<B * C,  512, 0, stream>>>(q, k, h, gv, ws, out);
}